// Round 11
// baseline (150.393 us; speedup 1.0000x reference)
//
#include <hip/hip_runtime.h>

typedef float f32x4 __attribute__((ext_vector_type(4)));
typedef __bf16 bf16x8 __attribute__((ext_vector_type(8)));
typedef unsigned short u16x8 __attribute__((ext_vector_type(8)));
typedef unsigned short u16x4 __attribute__((ext_vector_type(4)));

#define NB 4
#define NH 16
#define TT 4096
#define DD 64
#define LOG2E 1.4426950408889634f
#define QSCALE (LOG2E * 0.125f)   // (1/sqrt(64)) * log2(e)
#define NEGB (-1.5e9f)            // large-negative (log2 domain); exp2 -> 0

// Per ping-pong buffer: K 256*64 u16 (32K) + V^T 64*256 u16 (32K) + bias 256 f32 (1K)
#define BUFB (256 * 64 * 2 + 64 * 256 * 2 + 256 * 4)   // 66560 B; x2 = 130 KiB

__device__ __forceinline__ unsigned cvt_pk_bf16(float a, float b) {
  unsigned r;
  asm("v_cvt_pk_bf16_f32 %0, %1, %2" : "=v"(r) : "v"(a), "v"(b));
  return r;   // lo16 = bf16(a), hi16 = bf16(b)  (RNE)
}
__device__ __forceinline__ float exp2_hw(float x) {
  float r;
  asm("v_exp_f32 %0, %1" : "=v"(r) : "v"(x));
  return r;
}
__device__ __forceinline__ float max3f(float a, float b, float c) {
  float r;
  asm("v_max3_f32 %0, %1, %2, %3" : "=v"(r) : "v"(a), "v"(b), "v"(c));
  return r;
}

// K tile [256][64] u16 row-major, XOR swizzle for b128 reads at row-stride 128B.
__device__ __forceinline__ int kswz(int key, int d) {
  return ((key << 6) + d) ^ ((key & 7) << 3);
}
// V^T tile [64][256] u16; 8B chunk index (key>>2) XORed with (d&15).
__device__ __forceinline__ int vtidx(int d, int key) {
  return (d << 8) + ((((key >> 2) ^ (d & 15)) << 2) | (key & 3));
}

__global__ __launch_bounds__(512, 2) void swa_fwd(
    const float* __restrict__ Qg, const float* __restrict__ Kg,
    const float* __restrict__ Vg, const float* __restrict__ Mg,
    float* __restrict__ Og) {
  extern __shared__ char smem[];   // 2 * BUFB = 133120 B -> 1 block/CU

  // 256 blocks; XCD-contiguous remap. Each block: one (b,h), 8 consecutive q-blocks.
  const int bid = blockIdx.x;
  const int flat = (bid & 7) * 32 + (bid >> 3);
  const int bh = flat >> 2;          // 0..63
  const int ibase = (flat & 3) * 8;  // 0,8,16,24
  const int b = bh >> 4;

  const int t = threadIdx.x;   // 0..511
  const int lane = t & 63;
  const int wid = t >> 6;      // 0..7
  const int lr = lane & 15;
  const int g = lane >> 4;

  const size_t base = (size_t)bh * (TT * DD);
  const float* Qb = Qg + base;
  const float* Kb = Kg + base;
  const float* Vb = Vg + base;
  const float* Mb = Mg + (size_t)b * TT;
  float* Og_ = Og + base;

  const int dg = (t & 7) * 8;   // 8 consecutive d per thread (staging)
  const int rowt = t >> 3;      // 64 keys per iter (512 threads)

  // ---- prefetch register state (live across compute of previous task) ----
  f32x4 ka[4][2], va[4][2], qraw[2][2], mrow;
  bf16x8 qbA[2], qbB[2];

  // issue: global -> regs for q-block i (no waits here)
  auto issue = [&](int i) {
    const int j0 = i * 128 - 128;
#pragma unroll
    for (int it = 0; it < 4; ++it) {
      int j = j0 + it * 64 + rowt;
      j = j < 0 ? 0 : j;               // clamp; masked via bias later
      const float* ks = Kb + (size_t)j * DD + dg;
      ka[it][0] = *(const f32x4*)ks;
      ka[it][1] = *(const f32x4*)(ks + 4);
    }
#pragma unroll
    for (int it = 0; it < 4; ++it) {
      int j = j0 + it * 64 + rowt;
      j = j < 0 ? 0 : j;
      const float* vs = Vb + (size_t)j * DD + dg;
      va[it][0] = *(const f32x4*)vs;
      va[it][1] = *(const f32x4*)(vs + 4);
    }
    const int qrow0 = i * 128 + wid * 16;
#pragma unroll
    for (int s = 0; s < 2; ++s) {
      const float* qp = Qb + (size_t)(qrow0 + lr) * DD + s * 32 + g * 8;
      qraw[s][0] = *(const f32x4*)qp;
      qraw[s][1] = *(const f32x4*)(qp + 4);
    }
    if (t < 64) {                      // wave 0 stages the 256-entry bias row
      int j = j0 + t * 4;
      mrow = (j >= 0) ? *(const f32x4*)(Mb + j) : (f32x4){0.f, 0.f, 0.f, 0.f};
    }
  };

  // commit: cvt + write regs -> LDS buffer (compiler inserts the vmcnt waits)
  auto commit = [&](char* buf, int i) {
    unsigned short* kh = (unsigned short*)buf;
    unsigned short* vt = kh + 256 * 64;
    float* bs = (float*)(vt + 64 * 256);
#pragma unroll
    for (int it = 0; it < 4; ++it) {
      int key = it * 64 + rowt;
      union { u16x8 v; unsigned w[4]; } hh;
      hh.w[0] = cvt_pk_bf16(ka[it][0][0], ka[it][0][1]);
      hh.w[1] = cvt_pk_bf16(ka[it][0][2], ka[it][0][3]);
      hh.w[2] = cvt_pk_bf16(ka[it][1][0], ka[it][1][1]);
      hh.w[3] = cvt_pk_bf16(ka[it][1][2], ka[it][1][3]);
      *(u16x8*)(kh + kswz(key, dg)) = hh.v;
    }
#pragma unroll
    for (int it = 0; it < 4; ++it) {
      int key = it * 64 + rowt;
      unsigned p0 = cvt_pk_bf16(va[it][0][0], va[it][0][1]);
      unsigned p1 = cvt_pk_bf16(va[it][0][2], va[it][0][3]);
      unsigned p2 = cvt_pk_bf16(va[it][1][0], va[it][1][1]);
      unsigned p3 = cvt_pk_bf16(va[it][1][2], va[it][1][3]);
      vt[vtidx(dg + 0, key)] = (unsigned short)p0;
      vt[vtidx(dg + 1, key)] = (unsigned short)(p0 >> 16);
      vt[vtidx(dg + 2, key)] = (unsigned short)p1;
      vt[vtidx(dg + 3, key)] = (unsigned short)(p1 >> 16);
      vt[vtidx(dg + 4, key)] = (unsigned short)p2;
      vt[vtidx(dg + 5, key)] = (unsigned short)(p2 >> 16);
      vt[vtidx(dg + 6, key)] = (unsigned short)p3;
      vt[vtidx(dg + 7, key)] = (unsigned short)(p3 >> 16);
    }
    if (t < 64) {
      int j = (i * 128 - 128) + t * 4;
      f32x4 bb;
      if (j >= 0) {
        bb = mrow * LOG2E;
      } else {
        bb = (f32x4){NEGB, NEGB, NEGB, NEGB};
      }
      *(f32x4*)(bs + t * 4) = bb;
    }
#pragma unroll
    for (int s = 0; s < 2; ++s) {      // Q pack for the NEXT task
      union { unsigned w[4]; bf16x8 v; } H;
      H.w[0] = cvt_pk_bf16(qraw[s][0][0] * QSCALE, qraw[s][0][1] * QSCALE);
      H.w[1] = cvt_pk_bf16(qraw[s][0][2] * QSCALE, qraw[s][0][3] * QSCALE);
      H.w[2] = cvt_pk_bf16(qraw[s][1][0] * QSCALE, qraw[s][1][1] * QSCALE);
      H.w[3] = cvt_pk_bf16(qraw[s][1][2] * QSCALE, qraw[s][1][3] * QSCALE);
      qbB[s] = H.v;
    }
  };

  auto compute = [&](char* buf, int i) {
    unsigned short* kh = (unsigned short*)buf;
    unsigned short* vt = kh + 256 * 64;
    float* bs = (float*)(vt + 64 * 256);

    // QK: S^T = K * Q^T (swapped). 32 MFMA/wave.
    f32x4 acc[16];
#pragma unroll
    for (int mt = 0; mt < 16; ++mt)
      acc[mt] = (f32x4){0.f, 0.f, 0.f, 0.f};
#pragma unroll
    for (int mt = 0; mt < 16; ++mt)
#pragma unroll
      for (int s = 0; s < 2; ++s) {
        bf16x8 kf = *(const bf16x8*)(kh + kswz(mt * 16 + lr, s * 32 + g * 8));
        acc[mt] = __builtin_amdgcn_mfma_f32_16x16x32_bf16(kf, qbA[s], acc[mt], 0, 0, 0);
      }

    // full-row softmax (log2 domain). key = mt*16 + 4g + r ; qrow = lr
    float m = -1e38f;
#pragma unroll
    for (int mt = 0; mt < 16; ++mt) {
      f32x4 bv = *(const f32x4*)(bs + mt * 16 + 4 * g);   // broadcast read
#pragma unroll
      for (int r = 0; r < 4; ++r)
        acc[mt][r] += bv[r];
      m = max3f(acc[mt][0], acc[mt][1], m);
      m = max3f(acc[mt][2], acc[mt][3], m);
    }
    m = fmaxf(m, __shfl_xor(m, 16));
    m = fmaxf(m, __shfl_xor(m, 32));

    float l = 0.f;
#pragma unroll
    for (int mt = 0; mt < 16; ++mt)
#pragma unroll
      for (int r = 0; r < 4; ++r) {
        float p = exp2_hw(acc[mt][r] - m);
        acc[mt][r] = p;
        l += p;
      }
    l += __shfl_xor(l, 16);
    l += __shfl_xor(l, 32);
    const float inv = 1.f / l;

    // PV: A = P (regs), B = V^T from LDS; per-slot key permutation matched.
    f32x4 oacc[4];
#pragma unroll
    for (int dt = 0; dt < 4; ++dt)
      oacc[dt] = (f32x4){0.f, 0.f, 0.f, 0.f};
#pragma unroll
    for (int c = 0; c < 8; ++c) {
      union { unsigned w[4]; bf16x8 v; } pa;
      pa.w[0] = cvt_pk_bf16(acc[2 * c][0], acc[2 * c][1]);
      pa.w[1] = cvt_pk_bf16(acc[2 * c][2], acc[2 * c][3]);
      pa.w[2] = cvt_pk_bf16(acc[2 * c + 1][0], acc[2 * c + 1][1]);
      pa.w[3] = cvt_pk_bf16(acc[2 * c + 1][2], acc[2 * c + 1][3]);
#pragma unroll
      for (int dt = 0; dt < 4; ++dt) {
        int d = dt * 16 + lr;                 // d&15 == lr
        union { u16x4 h[2]; bf16x8 v; } vb;
        vb.h[0] = *(const u16x4*)(vt + (d << 8) + ((((8 * c) | g) ^ lr) << 2));
        vb.h[1] = *(const u16x4*)(vt + (d << 8) + ((((8 * c + 4) | g) ^ lr) << 2));
        oacc[dt] = __builtin_amdgcn_mfma_f32_16x16x32_bf16(pa.v, vb.v, oacc[dt], 0, 0, 0);
      }
    }

    // epilogue: row = 4g + r (local), col = dt*16 + lr
    const int qrow0 = i * 128 + wid * 16;
    float* Ob = Og_ + (size_t)qrow0 * DD;
#pragma unroll
    for (int r = 0; r < 4; ++r) {
      float iv = __shfl(inv, 4 * g + r);
      int row = 4 * g + r;
#pragma unroll
      for (int dt = 0; dt < 4; ++dt)
        Ob[(size_t)row * DD + dt * 16 + lr] = oacc[dt][r] * iv;
    }
  };

  // ---- prologue ----
  issue(ibase);
  commit(smem, ibase);
  qbA[0] = qbB[0];
  qbA[1] = qbB[1];
  __syncthreads();

  // ---- task pipeline: loads for t+1 in flight during compute of t ----
  int cur = 0;
#pragma unroll 1
  for (int tt = 0; tt < 8; ++tt) {
    const int i = ibase + tt;
    if (tt < 7) issue(i + 1);
    compute(smem + cur * BUFB, i);
    if (tt < 7) {
      commit(smem + (cur ^ 1) * BUFB, i + 1);
      qbA[0] = qbB[0];
      qbA[1] = qbB[1];
      __syncthreads();
      cur ^= 1;
    }
  }
}

extern "C" void kernel_launch(void* const* d_in, const int* in_sizes, int n_in,
                              void* d_out, int out_size, void* d_ws, size_t ws_size,
                              hipStream_t stream) {
  (void)in_sizes; (void)n_in; (void)out_size; (void)d_ws; (void)ws_size;
  const float* Q = (const float*)d_in[0];
  const float* K = (const float*)d_in[1];
  const float* V = (const float*)d_in[2];
  const float* M = (const float*)d_in[3];
  float* O = (float*)d_out;

  const int shmem = 2 * BUFB;   // 133120 B
  (void)hipFuncSetAttribute((const void*)swa_fwd,
                            hipFuncAttributeMaxDynamicSharedMemorySize, shmem);
  hipLaunchKernelGGL(swa_fwd, dim3(256), dim3(512), shmem, stream,
                     Q, K, V, M, O);
}

// Round 12
// 51.037 us; speedup vs baseline: 2.9467x; 2.9467x over previous
//
#include <hip/hip_runtime.h>

typedef float f32x4 __attribute__((ext_vector_type(4)));
typedef __bf16 bf16x8 __attribute__((ext_vector_type(8)));
typedef unsigned short u16x8 __attribute__((ext_vector_type(8)));
typedef unsigned short u16x4 __attribute__((ext_vector_type(4)));

#define NB 4
#define NH 16
#define TT 4096
#define DD 64
#define LOG2E 1.4426950408889634f
#define QSCALE (LOG2E * 0.125f)   // (1/sqrt(64)) * log2(e)
#define NEGB (-1.5e9f)            // large-negative (log2 domain); exp2 -> 0

__device__ __forceinline__ unsigned cvt_pk_bf16(float a, float b) {
  unsigned r;
  asm("v_cvt_pk_bf16_f32 %0, %1, %2" : "=v"(r) : "v"(a), "v"(b));
  return r;   // lo16 = bf16(a), hi16 = bf16(b)  (RNE)
}
__device__ __forceinline__ float exp2_hw(float x) {
  float r;
  asm("v_exp_f32 %0, %1" : "=v"(r) : "v"(x));
  return r;
}
__device__ __forceinline__ float max3f(float a, float b, float c) {
  float r;
  asm("v_max3_f32 %0, %1, %2, %3" : "=v"(r) : "v"(a), "v"(b), "v"(c));
  return r;
}

// K tile [256][64] u16 row-major, XOR swizzle for b128 reads at row-stride 128B.
__device__ __forceinline__ int kswz(int key, int d) {
  return ((key << 6) + d) ^ ((key & 7) << 3);
}
// V^T tile [64][256] u16, slot-permuted within 32-key chunks so one lane's 8
// PV-B keys {32c+16hi+4g+r} are ONE contiguous 16B chunk in jj=r+4*hi order:
//   slot(k) = (k&3) | ((k>>4)&1)<<2 | ((k>>2)&3)<<3   (within k&31)
//   16B-chunk index c16(k) = (k>>5)*4 + ((k>>2)&3), swizzled by d.
__device__ __forceinline__ int cswz(int d, int c16) {
  return c16 ^ (d & 7) ^ ((d >> 3) & 7);
}
__device__ __forceinline__ int vtidx(int d, int key) {
  int c16 = ((key >> 5) << 2) + ((key >> 2) & 3);
  int low3 = (key & 3) | (((key >> 4) & 1) << 2);
  return (d << 8) + (cswz(d, c16) << 3) + low3;
}

__global__ __launch_bounds__(512, 4) void swa_fwd(
    const float* __restrict__ Qg, const float* __restrict__ Kg,
    const float* __restrict__ Vg, const float* __restrict__ Mg,
    float* __restrict__ Og) {
  // 65.5 KiB static LDS -> 2 blocks/CU; 8 waves/block -> 4 waves/SIMD (128-reg cap).
  __shared__ unsigned short khs[256 * 64];   // 32 KiB  K  (bf16, kswz)
  __shared__ unsigned short vts[64 * 256];   // 32 KiB  V^T (bf16, slot+cswz)
  __shared__ float bs[256];                  // 1 KiB   bias (mask*log2e / NEGB)

  // XCD-bijective swizzle: 2048 blocks, 8 XCDs, contiguous work per XCD.
  const int bid = blockIdx.x;
  const int flat = (bid & 7) * 256 + (bid >> 3);
  const int i = flat & 31;        // q-block
  const int bh = flat >> 5;       // b*NH + h
  const int b = bh >> 4;

  const int t = threadIdx.x;      // 0..511
  const int lane = t & 63;
  const int wid = t >> 6;         // 0..7
  const int lr = lane & 15;
  const int g = lane >> 4;

  const size_t base = (size_t)bh * (TT * DD);
  const float* Qb = Qg + base;
  const float* Kb = Kg + base;
  const float* Vb = Vg + base;
  const float* Mb = Mg + (size_t)b * TT;
  const int j0 = i * 128 - 128;           // window start (may be -128 for i==0)
  const int qrow0 = i * 128 + wid * 16;   // this wave's 16 rows

  // ---- Q loads (16 rows/wave): row = qrow0 + lr, d = s*32 + g*8 .. +8 ----
  f32x4 qraw[2][2];
#pragma unroll
  for (int s = 0; s < 2; ++s) {
    const float* qp = Qb + (size_t)(qrow0 + lr) * DD + s * 32 + g * 8;
    qraw[s][0] = *(const f32x4*)qp;
    qraw[s][1] = *(const f32x4*)(qp + 4);
  }

  const int dg = (t & 7) * 8;     // 8 consecutive d per thread
  const int rowt = t >> 3;        // 64 keys per iter (512 threads)

  // ---- burst-load K and V tiles into registers (16 loads in flight) ----
  f32x4 ka[4][2], va[4][2];
#pragma unroll
  for (int it = 0; it < 4; ++it) {
    int j = j0 + it * 64 + rowt;
    j = j < 0 ? 0 : j;            // clamp; invalid keys masked via bias later
    const float* ks = Kb + (size_t)j * DD + dg;
    ka[it][0] = *(const f32x4*)ks;
    ka[it][1] = *(const f32x4*)(ks + 4);
  }
#pragma unroll
  for (int it = 0; it < 4; ++it) {
    int j = j0 + it * 64 + rowt;
    j = j < 0 ? 0 : j;
    const float* vs = Vb + (size_t)j * DD + dg;
    va[it][0] = *(const f32x4*)vs;
    va[it][1] = *(const f32x4*)(vs + 4);
  }
  // wave 0: mask row (4 keys/lane), issued in the same burst
  f32x4 mrow = (f32x4){0.f, 0.f, 0.f, 0.f};
  if (t < 64) {
    int j = j0 + t * 4;
    if (j >= 0) mrow = *(const f32x4*)(Mb + j);
  }

  // ---- convert + write K (b128, swizzled) ----
#pragma unroll
  for (int it = 0; it < 4; ++it) {
    int key = it * 64 + rowt;
    union { u16x8 v; unsigned w[4]; } hh;
    hh.w[0] = cvt_pk_bf16(ka[it][0][0], ka[it][0][1]);
    hh.w[1] = cvt_pk_bf16(ka[it][0][2], ka[it][0][3]);
    hh.w[2] = cvt_pk_bf16(ka[it][1][0], ka[it][1][1]);
    hh.w[3] = cvt_pk_bf16(ka[it][1][2], ka[it][1][3]);
    *(u16x8*)(khs + kswz(key, dg)) = hh.v;
  }

  // ---- convert + write V^T (8 scalar u16 per iter, slot+cswz layout) ----
#pragma unroll
  for (int it = 0; it < 4; ++it) {
    int key = it * 64 + rowt;
    unsigned p0 = cvt_pk_bf16(va[it][0][0], va[it][0][1]);
    unsigned p1 = cvt_pk_bf16(va[it][0][2], va[it][0][3]);
    unsigned p2 = cvt_pk_bf16(va[it][1][0], va[it][1][1]);
    unsigned p3 = cvt_pk_bf16(va[it][1][2], va[it][1][3]);
    vts[vtidx(dg + 0, key)] = (unsigned short)p0;
    vts[vtidx(dg + 1, key)] = (unsigned short)(p0 >> 16);
    vts[vtidx(dg + 2, key)] = (unsigned short)p1;
    vts[vtidx(dg + 3, key)] = (unsigned short)(p1 >> 16);
    vts[vtidx(dg + 4, key)] = (unsigned short)p2;
    vts[vtidx(dg + 5, key)] = (unsigned short)(p2 >> 16);
    vts[vtidx(dg + 6, key)] = (unsigned short)p3;
    vts[vtidx(dg + 7, key)] = (unsigned short)(p3 >> 16);
  }

  // ---- wave 0: commit bias (mask*log2e, NEGB for invalid keys) ----
  if (t < 64) {
    int j = j0 + t * 4;
    f32x4 bb;
    if (j >= 0) {
      bb = mrow * LOG2E;
    } else {
      bb = (f32x4){NEGB, NEGB, NEGB, NEGB};
    }
    *(f32x4*)(bs + t * 4) = bb;
  }

  // ---- Q fragments: plain bf16 of q * (log2e/8) ----
  bf16x8 qb[2];
#pragma unroll
  for (int s = 0; s < 2; ++s) {
    union { unsigned w[4]; bf16x8 v; } H;
    H.w[0] = cvt_pk_bf16(qraw[s][0][0] * QSCALE, qraw[s][0][1] * QSCALE);
    H.w[1] = cvt_pk_bf16(qraw[s][0][2] * QSCALE, qraw[s][0][3] * QSCALE);
    H.w[2] = cvt_pk_bf16(qraw[s][1][0] * QSCALE, qraw[s][1][1] * QSCALE);
    H.w[3] = cvt_pk_bf16(qraw[s][1][2] * QSCALE, qraw[s][1][3] * QSCALE);
    qb[s] = H.v;
  }

  __syncthreads();   // K, V^T, bias ready (the only barrier)

  // ---- QK: S^T = K * Q^T (swapped). 32 MFMA/wave. ----
  f32x4 acc[16];
#pragma unroll
  for (int mt = 0; mt < 16; ++mt)
    acc[mt] = (f32x4){0.f, 0.f, 0.f, 0.f};

#pragma unroll
  for (int mt = 0; mt < 16; ++mt)
#pragma unroll
    for (int s = 0; s < 2; ++s) {
      bf16x8 kf = *(const bf16x8*)(khs + kswz(mt * 16 + lr, s * 32 + g * 8));
      acc[mt] = __builtin_amdgcn_mfma_f32_16x16x32_bf16(kf, qb[s], acc[mt], 0, 0, 0);
    }

  // ---- full-row softmax (log2 domain). lane value (mt,r):
  //   key = mt*16 + 4g + r ; qrow = lr.  Bias from LDS (broadcast reads).
  float m = -1e38f;
#pragma unroll
  for (int mt = 0; mt < 16; ++mt) {
    f32x4 bv = *(const f32x4*)(bs + mt * 16 + 4 * g);
#pragma unroll
    for (int r = 0; r < 4; ++r)
      acc[mt][r] += bv[r];
    m = max3f(acc[mt][0], acc[mt][1], m);
    m = max3f(acc[mt][2], acc[mt][3], m);
  }
  m = fmaxf(m, __shfl_xor(m, 16));
  m = fmaxf(m, __shfl_xor(m, 32));

  float l = 0.f;
#pragma unroll
  for (int mt = 0; mt < 16; ++mt)
#pragma unroll
    for (int r = 0; r < 4; ++r) {
      float p = exp2_hw(acc[mt][r] - m);
      acc[mt][r] = p;
      l += p;
    }
  l += __shfl_xor(l, 16);
  l += __shfl_xor(l, 32);
  const float inv = 1.f / l;

  // ---- PV: out = P * V.  A = P (regs, natural layout), B = V^T via single
  // b128 per (c,dt): chunk (4c+g) ^ swz at row d holds keys in jj order.
  f32x4 oacc[4];
#pragma unroll
  for (int dt = 0; dt < 4; ++dt)
    oacc[dt] = (f32x4){0.f, 0.f, 0.f, 0.f};

#pragma unroll
  for (int c = 0; c < 8; ++c) {
    union { unsigned w[4]; bf16x8 v; } pa;
    pa.w[0] = cvt_pk_bf16(acc[2 * c][0], acc[2 * c][1]);
    pa.w[1] = cvt_pk_bf16(acc[2 * c][2], acc[2 * c][3]);
    pa.w[2] = cvt_pk_bf16(acc[2 * c + 1][0], acc[2 * c + 1][1]);
    pa.w[3] = cvt_pk_bf16(acc[2 * c + 1][2], acc[2 * c + 1][3]);
#pragma unroll
    for (int dt = 0; dt < 4; ++dt) {
      int d = dt * 16 + lr;
      bf16x8 vb = *(const bf16x8*)(vts + (d << 8) + (cswz(d, 4 * c + g) << 3));
      oacc[dt] = __builtin_amdgcn_mfma_f32_16x16x32_bf16(pa.v, vb,
                                                         oacc[dt], 0, 0, 0);
    }
  }

  // ---- epilogue: C layout -> row = 4g + r (local), col = dt*16 + lr ----
  float* Ob = Og + base + (size_t)qrow0 * DD;
#pragma unroll
  for (int r = 0; r < 4; ++r) {
    float iv = __shfl(inv, 4 * g + r);      // lane 4g+r holds q = 4g+r
    int row = 4 * g + r;
#pragma unroll
    for (int dt = 0; dt < 4; ++dt)
      Ob[(size_t)row * DD + dt * 16 + lr] = oacc[dt][r] * iv;
  }
}

extern "C" void kernel_launch(void* const* d_in, const int* in_sizes, int n_in,
                              void* d_out, int out_size, void* d_ws, size_t ws_size,
                              hipStream_t stream) {
  (void)in_sizes; (void)n_in; (void)out_size; (void)d_ws; (void)ws_size;
  const float* Q = (const float*)d_in[0];
  const float* K = (const float*)d_in[1];
  const float* V = (const float*)d_in[2];
  const float* M = (const float*)d_in[3];
  float* O = (float*)d_out;

  hipLaunchKernelGGL(swa_fwd, dim3(NB * NH * 32), dim3(512), 0, stream,
                     Q, K, V, M, O);
}

// Round 13
// 50.573 us; speedup vs baseline: 2.9738x; 1.0092x over previous
//
#include <hip/hip_runtime.h>

typedef float f32x4 __attribute__((ext_vector_type(4)));
typedef __bf16 bf16x8 __attribute__((ext_vector_type(8)));
typedef unsigned short u16x8 __attribute__((ext_vector_type(8)));
typedef unsigned u32x2 __attribute__((ext_vector_type(2)));

#define NB 4
#define NH 16
#define TT 4096
#define DD 64
#define LOG2E 1.4426950408889634f
#define QSCALE (LOG2E * 0.125f)   // (1/sqrt(64)) * log2(e)
#define NEGB (-1.5e9f)            // large-negative (log2 domain); exp2 -> 0

__device__ __forceinline__ unsigned cvt_pk_bf16(float a, float b) {
  unsigned r;
  asm("v_cvt_pk_bf16_f32 %0, %1, %2" : "=v"(r) : "v"(a), "v"(b));
  return r;   // lo16 = bf16(a), hi16 = bf16(b)  (RNE)
}
__device__ __forceinline__ float exp2_hw(float x) {
  float r;
  asm("v_exp_f32 %0, %1" : "=v"(r) : "v"(x));
  return r;
}
__device__ __forceinline__ float max3f(float a, float b, float c) {
  float r;
  asm("v_max3_f32 %0, %1, %2, %3" : "=v"(r) : "v"(a), "v"(b), "v"(c));
  return r;
}

// K tile [256][64] u16 row-major, XOR swizzle for b128 reads at row-stride 128B.
__device__ __forceinline__ int kswz(int key, int d) {
  return ((key << 6) + d) ^ ((key & 7) << 3);
}
// V^T tile [64][256] u16, slot-permuted within 32-key chunks so one lane's 8
// PV-B keys {32c+16hi+4g+r} are ONE contiguous 16B chunk in jj=r+4*hi order:
//   u16 slot within chunk = (key&3) | ((key>>4)&1)<<2
//   16B-chunk index c16(key) = (key>>5)*4 + ((key>>2)&3), swizzled by d.
__device__ __forceinline__ int cswz(int d, int c16) {
  return c16 ^ (d & 7) ^ ((d >> 3) & 7);
}

__global__ __launch_bounds__(512, 4) void swa_fwd(
    const float* __restrict__ Qg, const float* __restrict__ Kg,
    const float* __restrict__ Vg, const float* __restrict__ Mg,
    float* __restrict__ Og) {
  // 65.5 KiB static LDS -> 2 blocks/CU; 8 waves/block -> 4 waves/SIMD (128-reg cap).
  __shared__ unsigned short khs[256 * 64];   // 32 KiB  K  (bf16, kswz)
  __shared__ unsigned short vts[64 * 256];   // 32 KiB  V^T (bf16, slot+cswz)
  __shared__ float bs[256];                  // 1 KiB   bias (mask*log2e / NEGB)

  // XCD-bijective swizzle: 2048 blocks, 8 XCDs, contiguous work per XCD.
  const int bid = blockIdx.x;
  const int flat = (bid & 7) * 256 + (bid >> 3);
  const int i = flat & 31;        // q-block
  const int bh = flat >> 5;       // b*NH + h
  const int b = bh >> 4;

  const int t = threadIdx.x;      // 0..511
  const int lane = t & 63;
  const int wid = t >> 6;         // 0..7
  const int lr = lane & 15;
  const int g = lane >> 4;

  const size_t base = (size_t)bh * (TT * DD);
  const float* Qb = Qg + base;
  const float* Kb = Kg + base;
  const float* Vb = Vg + base;
  const float* Mb = Mg + (size_t)b * TT;
  const int j0 = i * 128 - 128;           // window start (may be -128 for i==0)
  const int qrow0 = i * 128 + wid * 16;   // this wave's 16 rows

  // ---- Q loads (16 rows/wave): row = qrow0 + lr, d = s*32 + g*8 .. +8 ----
  f32x4 qraw[2][2];
#pragma unroll
  for (int s = 0; s < 2; ++s) {
    const float* qp = Qb + (size_t)(qrow0 + lr) * DD + s * 32 + g * 8;
    qraw[s][0] = *(const f32x4*)qp;
    qraw[s][1] = *(const f32x4*)(qp + 4);
  }

  const int dg = (t & 7) * 8;     // 8 consecutive d per thread
  const int rowt = t >> 3;        // K staging: 64 keys per iter
  const int kb = (t >> 3) * 4;    // V staging: 4 consecutive keys per thread

  // ---- burst-load K (it-based rows) and V (4 consecutive keys) ----
  f32x4 ka[4][2], va[4][2];
#pragma unroll
  for (int it = 0; it < 4; ++it) {
    int j = j0 + it * 64 + rowt;
    j = j < 0 ? 0 : j;            // clamp; invalid keys masked via bias later
    const float* ks = Kb + (size_t)j * DD + dg;
    ka[it][0] = *(const f32x4*)ks;
    ka[it][1] = *(const f32x4*)(ks + 4);
  }
#pragma unroll
  for (int k = 0; k < 4; ++k) {
    int j = j0 + kb + k;
    j = j < 0 ? 0 : j;
    const float* vs = Vb + (size_t)j * DD + dg;
    va[k][0] = *(const f32x4*)vs;
    va[k][1] = *(const f32x4*)(vs + 4);
  }
  // wave 0: mask row (4 keys/lane), issued in the same burst
  f32x4 mrow = (f32x4){0.f, 0.f, 0.f, 0.f};
  if (t < 64) {
    int j = j0 + t * 4;
    if (j >= 0) mrow = *(const f32x4*)(Mb + j);
  }

  // ---- convert + write K (b128, swizzled) ----
#pragma unroll
  for (int it = 0; it < 4; ++it) {
    int key = it * 64 + rowt;
    union { u16x8 v; unsigned w[4]; } hh;
    hh.w[0] = cvt_pk_bf16(ka[it][0][0], ka[it][0][1]);
    hh.w[1] = cvt_pk_bf16(ka[it][0][2], ka[it][0][3]);
    hh.w[2] = cvt_pk_bf16(ka[it][1][0], ka[it][1][1]);
    hh.w[3] = cvt_pk_bf16(ka[it][1][2], ka[it][1][3]);
    *(u16x8*)(khs + kswz(key, dg)) = hh.v;
  }

  // ---- convert + write V^T: per d-row one b64 = 4 consecutive keys ----
  {
    const int c16v = ((kb >> 5) << 2) | ((kb >> 2) & 3);
    const int hiv = ((kb >> 4) & 1) << 2;          // u16 offset within chunk
#pragma unroll
    for (int h = 0; h < 2; ++h)
#pragma unroll
      for (int e = 0; e < 4; ++e) {
        int d = dg + h * 4 + e;
        u32x2 ww;
        ww.x = cvt_pk_bf16(va[0][h][e], va[1][h][e]);   // keys kb, kb+1
        ww.y = cvt_pk_bf16(va[2][h][e], va[3][h][e]);   // keys kb+2, kb+3
        *(u32x2*)(vts + (d << 8) + (cswz(d, c16v) << 3) + hiv) = ww;
      }
  }

  // ---- wave 0: commit bias (mask*log2e, NEGB for invalid keys) ----
  if (t < 64) {
    int j = j0 + t * 4;
    f32x4 bb;
    if (j >= 0) {
      bb = mrow * LOG2E;
    } else {
      bb = (f32x4){NEGB, NEGB, NEGB, NEGB};
    }
    *(f32x4*)(bs + t * 4) = bb;
  }

  // ---- Q fragments: plain bf16 of q * (log2e/8) ----
  bf16x8 qb[2];
#pragma unroll
  for (int s = 0; s < 2; ++s) {
    union { unsigned w[4]; bf16x8 v; } H;
    H.w[0] = cvt_pk_bf16(qraw[s][0][0] * QSCALE, qraw[s][0][1] * QSCALE);
    H.w[1] = cvt_pk_bf16(qraw[s][0][2] * QSCALE, qraw[s][0][3] * QSCALE);
    H.w[2] = cvt_pk_bf16(qraw[s][1][0] * QSCALE, qraw[s][1][1] * QSCALE);
    H.w[3] = cvt_pk_bf16(qraw[s][1][2] * QSCALE, qraw[s][1][3] * QSCALE);
    qb[s] = H.v;
  }

  __syncthreads();   // K, V^T, bias ready (the only barrier)

  // ---- QK: acc preloaded with bias; S^T = K * Q^T accumulates on top. ----
  // lane value (mt,r): key = mt*16 + 4g + r ; qrow = lr
  f32x4 acc[16];
#pragma unroll
  for (int mt = 0; mt < 16; ++mt)
    acc[mt] = *(const f32x4*)(bs + mt * 16 + 4 * g);

#pragma unroll
  for (int mt = 0; mt < 16; ++mt)
#pragma unroll
    for (int s = 0; s < 2; ++s) {
      bf16x8 kf = *(const bf16x8*)(khs + kswz(mt * 16 + lr, s * 32 + g * 8));
      acc[mt] = __builtin_amdgcn_mfma_f32_16x16x32_bf16(kf, qb[s], acc[mt], 0, 0, 0);
    }

  // ---- full-row softmax (log2 domain) ----
  float m = -1e38f;
#pragma unroll
  for (int mt = 0; mt < 16; ++mt) {
    m = max3f(acc[mt][0], acc[mt][1], m);
    m = max3f(acc[mt][2], acc[mt][3], m);
  }
  m = fmaxf(m, __shfl_xor(m, 16));
  m = fmaxf(m, __shfl_xor(m, 32));

  float l = 0.f;
#pragma unroll
  for (int mt = 0; mt < 16; ++mt)
#pragma unroll
    for (int r = 0; r < 4; ++r) {
      float p = exp2_hw(acc[mt][r] - m);
      acc[mt][r] = p;
      l += p;
    }
  l += __shfl_xor(l, 16);
  l += __shfl_xor(l, 32);
  const float inv = 1.f / l;

  // ---- PV: out = P * V.  A = P (regs, natural layout), B = V^T via single
  // b128 per (c,dt): chunk (4c+g) ^ swz at row d holds keys in jj order.
  f32x4 oacc[4];
#pragma unroll
  for (int dt = 0; dt < 4; ++dt)
    oacc[dt] = (f32x4){0.f, 0.f, 0.f, 0.f};

#pragma unroll
  for (int c = 0; c < 8; ++c) {
    union { unsigned w[4]; bf16x8 v; } pa;
    pa.w[0] = cvt_pk_bf16(acc[2 * c][0], acc[2 * c][1]);
    pa.w[1] = cvt_pk_bf16(acc[2 * c][2], acc[2 * c][3]);
    pa.w[2] = cvt_pk_bf16(acc[2 * c + 1][0], acc[2 * c + 1][1]);
    pa.w[3] = cvt_pk_bf16(acc[2 * c + 1][2], acc[2 * c + 1][3]);
#pragma unroll
    for (int dt = 0; dt < 4; ++dt) {
      int d = dt * 16 + lr;
      bf16x8 vb = *(const bf16x8*)(vts + (d << 8) + (cswz(d, 4 * c + g) << 3));
      oacc[dt] = __builtin_amdgcn_mfma_f32_16x16x32_bf16(pa.v, vb,
                                                         oacc[dt], 0, 0, 0);
    }
  }

  // ---- epilogue: C layout -> row = 4g + r (local), col = dt*16 + lr ----
  float* Ob = Og + base + (size_t)qrow0 * DD;
#pragma unroll
  for (int r = 0; r < 4; ++r) {
    float iv = __shfl(inv, 4 * g + r);      // lane 4g+r holds q = 4g+r
    int row = 4 * g + r;
#pragma unroll
    for (int dt = 0; dt < 4; ++dt)
      Ob[(size_t)row * DD + dt * 16 + lr] = oacc[dt][r] * iv;
  }
}

extern "C" void kernel_launch(void* const* d_in, const int* in_sizes, int n_in,
                              void* d_out, int out_size, void* d_ws, size_t ws_size,
                              hipStream_t stream) {
  (void)in_sizes; (void)n_in; (void)out_size; (void)d_ws; (void)ws_size;
  const float* Q = (const float*)d_in[0];
  const float* K = (const float*)d_in[1];
  const float* V = (const float*)d_in[2];
  const float* M = (const float*)d_in[3];
  float* O = (float*)d_out;

  hipLaunchKernelGGL(swa_fwd, dim3(NB * NH * 32), dim3(512), 0, stream,
                     Q, K, V, M, O);
}

// Round 15
// 50.509 us; speedup vs baseline: 2.9775x; 1.0013x over previous
//
#include <hip/hip_runtime.h>

typedef float f32x4 __attribute__((ext_vector_type(4)));
typedef __bf16 bf16x8 __attribute__((ext_vector_type(8)));
typedef unsigned short u16x8 __attribute__((ext_vector_type(8)));
typedef unsigned u32x2 __attribute__((ext_vector_type(2)));

#define NB 4
#define NH 16
#define TT 4096
#define DD 64
#define LOG2E 1.4426950408889634f
#define QSCALE (LOG2E * 0.125f)   // (1/sqrt(64)) * log2(e)
#define NEGB (-1.5e9f)            // large-negative (log2 domain); exp2 -> 0

__device__ __forceinline__ unsigned cvt_pk_bf16(float a, float b) {
  unsigned r;
  asm("v_cvt_pk_bf16_f32 %0, %1, %2" : "=v"(r) : "v"(a), "v"(b));
  return r;   // lo16 = bf16(a), hi16 = bf16(b)  (RNE)
}
__device__ __forceinline__ float exp2_hw(float x) {
  float r;
  asm("v_exp_f32 %0, %1" : "=v"(r) : "v"(x));
  return r;
}
__device__ __forceinline__ float max3f(float a, float b, float c) {
  float r;
  asm("v_max3_f32 %0, %1, %2, %3" : "=v"(r) : "v"(a), "v"(b), "v"(c));
  return r;
}

// K tile [256][64] u16 row-major, XOR swizzle for b128 reads at row-stride 128B.
__device__ __forceinline__ int kswz(int key, int d) {
  return ((key << 6) + d) ^ ((key & 7) << 3);
}
// V^T tile [64][256] u16, slot-permuted within 32-key chunks so one lane's 8
// PV-B keys {32c+16hi+4g+r} are ONE contiguous 16B chunk in jj=r+4*hi order:
//   u16 slot within chunk = (key&3) | ((key>>4)&1)<<2
//   16B-chunk index c16(key) = (key>>5)*4 + ((key>>2)&3), swizzled by d.
__device__ __forceinline__ int cswz(int d, int c16) {
  return c16 ^ (d & 7) ^ ((d >> 3) & 7);
}

__global__ __launch_bounds__(512, 4) void swa_fwd(
    const float* __restrict__ Qg, const float* __restrict__ Kg,
    const float* __restrict__ Vg, const float* __restrict__ Mg,
    float* __restrict__ Og) {
  // 65.5 KiB static LDS -> 2 blocks/CU; 8 waves/block -> 4 waves/SIMD (128-reg cap).
  __shared__ unsigned short khs[256 * 64];   // 32 KiB  K  (bf16, kswz)
  __shared__ unsigned short vts[64 * 256];   // 32 KiB  V^T (bf16, slot+cswz)
  __shared__ float bs[256];                  // 1 KiB   bias (mask*log2e / NEGB)

  // XCD-bijective swizzle: 2048 blocks, 8 XCDs, contiguous work per XCD.
  const int bid = blockIdx.x;
  const int flat = (bid & 7) * 256 + (bid >> 3);
  const int i = flat & 31;        // q-block
  const int bh = flat >> 5;       // b*NH + h
  const int b = bh >> 4;

  const int t = threadIdx.x;      // 0..511
  const int lane = t & 63;
  const int wid = t >> 6;         // 0..7
  const int lr = lane & 15;
  const int g = lane >> 4;

  const size_t base = (size_t)bh * (TT * DD);
  const float* Qb = Qg + base;
  const float* Kb = Kg + base;
  const float* Vb = Vg + base;
  const float* Mb = Mg + (size_t)b * TT;
  const int j0 = i * 128 - 128;           // window start (may be -128 for i==0)
  const int qrow0 = i * 128 + wid * 16;   // this wave's 16 rows

  const int dg = (t & 7) * 8;     // 8 consecutive d per thread
  const int rowt = t >> 3;        // K staging: 64 keys per iter
  const int kb = (t >> 3) * 4;    // V staging: 4 consecutive keys per thread

  // ---- issue order matters for vmcnt: K first, then Q, mask, V LAST.
  // Every load below is executed by EVERY wave (no wave-asymmetric vmcnt).
  f32x4 ka[4][2];
#pragma unroll
  for (int it = 0; it < 4; ++it) {
    int j = j0 + it * 64 + rowt;
    j = j < 0 ? 0 : j;            // clamp; invalid keys masked via bias later
    const float* ks = Kb + (size_t)j * DD + dg;
    ka[it][0] = *(const f32x4*)ks;
    ka[it][1] = *(const f32x4*)(ks + 4);
  }
  f32x4 qraw[2][2];
#pragma unroll
  for (int s = 0; s < 2; ++s) {
    const float* qp = Qb + (size_t)(qrow0 + lr) * DD + s * 32 + g * 8;
    qraw[s][0] = *(const f32x4*)qp;
    qraw[s][1] = *(const f32x4*)(qp + 4);
  }
  // mask row: ALL waves load the same 256 entries (4/lane), clamped address.
  const int jm = j0 + (lane << 2);
  const int jmc = jm < 0 ? 0 : jm;
  f32x4 mrow = *(const f32x4*)(Mb + jmc);
  // V issued LAST; waited only after softmax.
  f32x4 va[4][2];
#pragma unroll
  for (int k = 0; k < 4; ++k) {
    int j = j0 + kb + k;
    j = j < 0 ? 0 : j;
    const float* vs = Vb + (size_t)j * DD + dg;
    va[k][0] = *(const f32x4*)vs;
    va[k][1] = *(const f32x4*)(vs + 4);
  }

  // ---- convert + write K (b128, swizzled); waits only on K loads ----
#pragma unroll
  for (int it = 0; it < 4; ++it) {
    int key = it * 64 + rowt;
    union { u16x8 v; unsigned w[4]; } hh;
    hh.w[0] = cvt_pk_bf16(ka[it][0][0], ka[it][0][1]);
    hh.w[1] = cvt_pk_bf16(ka[it][0][2], ka[it][0][3]);
    hh.w[2] = cvt_pk_bf16(ka[it][1][0], ka[it][1][1]);
    hh.w[3] = cvt_pk_bf16(ka[it][1][2], ka[it][1][3]);
    *(u16x8*)(khs + kswz(key, dg)) = hh.v;
  }

  // ---- bias commit: ALL waves write identical values (benign WW race) ----
  {
    f32x4 bb;
    if (jm >= 0) {
      bb = mrow * LOG2E;
    } else {
      bb = (f32x4){NEGB, NEGB, NEGB, NEGB};
    }
    *(f32x4*)(bs + (lane << 2)) = bb;
  }

  // ---- Q fragments: plain bf16 of q * (log2e/8) ----
  bf16x8 qb[2];
#pragma unroll
  for (int s = 0; s < 2; ++s) {
    union { unsigned w[4]; bf16x8 v; } H;
    H.w[0] = cvt_pk_bf16(qraw[s][0][0] * QSCALE, qraw[s][0][1] * QSCALE);
    H.w[1] = cvt_pk_bf16(qraw[s][0][2] * QSCALE, qraw[s][0][3] * QSCALE);
    H.w[2] = cvt_pk_bf16(qraw[s][1][0] * QSCALE, qraw[s][1][1] * QSCALE);
    H.w[3] = cvt_pk_bf16(qraw[s][1][2] * QSCALE, qraw[s][1][3] * QSCALE);
    qb[s] = H.v;
  }

  __syncthreads();   // barrier 1: khs + bias ready (V loads still in flight)

  // ---- QK: acc preloaded with bias; S^T = K * Q^T accumulates on top. ----
  // lane value (mt,r): key = mt*16 + 4g + r ; qrow = lr
  f32x4 acc[16];
#pragma unroll
  for (int mt = 0; mt < 16; ++mt)
    acc[mt] = *(const f32x4*)(bs + mt * 16 + 4 * g);

#pragma unroll
  for (int mt = 0; mt < 16; ++mt)
#pragma unroll
    for (int s = 0; s < 2; ++s) {
      bf16x8 kf = *(const bf16x8*)(khs + kswz(mt * 16 + lr, s * 32 + g * 8));
      acc[mt] = __builtin_amdgcn_mfma_f32_16x16x32_bf16(kf, qb[s], acc[mt], 0, 0, 0);
    }

  // ---- full-row softmax (log2 domain) ----
  float m = -1e38f;
#pragma unroll
  for (int mt = 0; mt < 16; ++mt) {
    m = max3f(acc[mt][0], acc[mt][1], m);
    m = max3f(acc[mt][2], acc[mt][3], m);
  }
  m = fmaxf(m, __shfl_xor(m, 16));
  m = fmaxf(m, __shfl_xor(m, 32));

  float l = 0.f;
#pragma unroll
  for (int mt = 0; mt < 16; ++mt)
#pragma unroll
    for (int r = 0; r < 4; ++r) {
      float p = exp2_hw(acc[mt][r] - m);
      acc[mt][r] = p;
      l += p;
    }
  l += __shfl_xor(l, 16);
  l += __shfl_xor(l, 32);
  const float inv = 1.f / l;

  // ---- NOW wait V + convert + write V^T (one b64 per d-row) ----
  {
    const int c16v = ((kb >> 5) << 2) | ((kb >> 2) & 3);
    const int hiv = ((kb >> 4) & 1) << 2;          // u16 offset within chunk
#pragma unroll
    for (int h = 0; h < 2; ++h)
#pragma unroll
      for (int e = 0; e < 4; ++e) {
        int d = dg + h * 4 + e;
        u32x2 ww;
        ww.x = cvt_pk_bf16(va[0][h][e], va[1][h][e]);   // keys kb, kb+1
        ww.y = cvt_pk_bf16(va[2][h][e], va[3][h][e]);   // keys kb+2, kb+3
        *(u32x2*)(vts + (d << 8) + (cswz(d, c16v) << 3) + hiv) = ww;
      }
  }

  __syncthreads();   // barrier 2: vts ready

  // ---- PV: out = P * V.  A = P (regs, natural layout), B = V^T via single
  // b128 per (c,dt): chunk (4c+g) ^ swz at row d holds keys in jj order.
  f32x4 oacc[4];
#pragma unroll
  for (int dt = 0; dt < 4; ++dt)
    oacc[dt] = (f32x4){0.f, 0.f, 0.f, 0.f};

#pragma unroll
  for (int c = 0; c < 8; ++c) {
    union { unsigned w[4]; bf16x8 v; } pa;
    pa.w[0] = cvt_pk_bf16(acc[2 * c][0], acc[2 * c][1]);
    pa.w[1] = cvt_pk_bf16(acc[2 * c][2], acc[2 * c][3]);
    pa.w[2] = cvt_pk_bf16(acc[2 * c + 1][0], acc[2 * c + 1][1]);
    pa.w[3] = cvt_pk_bf16(acc[2 * c + 1][2], acc[2 * c + 1][3]);
#pragma unroll
    for (int dt = 0; dt < 4; ++dt) {
      int d = dt * 16 + lr;
      bf16x8 vb = *(const bf16x8*)(vts + (d << 8) + (cswz(d, 4 * c + g) << 3));
      oacc[dt] = __builtin_amdgcn_mfma_f32_16x16x32_bf16(pa.v, vb,
                                                         oacc[dt], 0, 0, 0);
    }
  }

  // ---- epilogue: C layout -> row = 4g + r (local), col = dt*16 + lr ----
  float* Ob = Og + base + (size_t)qrow0 * DD;
#pragma unroll
  for (int r = 0; r < 4; ++r) {
    float iv = __shfl(inv, 4 * g + r);      // lane 4g+r holds q = 4g+r
    int row = 4 * g + r;
#pragma unroll
    for (int dt = 0; dt < 4; ++dt)
      Ob[(size_t)row * DD + dt * 16 + lr] = oacc[dt][r] * iv;
  }
}

extern "C" void kernel_launch(void* const* d_in, const int* in_sizes, int n_in,
                              void* d_out, int out_size, void* d_ws, size_t ws_size,
                              hipStream_t stream) {
  (void)in_sizes; (void)n_in; (void)out_size; (void)d_ws; (void)ws_size;
  const float* Q = (const float*)d_in[0];
  const float* K = (const float*)d_in[1];
  const float* V = (const float*)d_in[2];
  const float* M = (const float*)d_in[3];
  float* O = (float*)d_out;

  hipLaunchKernelGGL(swa_fwd, dim3(NB * NH * 32), dim3(512), 0, stream,
                     Q, K, V, M, O);
}